// Round 2
// baseline (2293.772 us; speedup 1.0000x reference)
//
#include <hip/hip_runtime.h>
#include <hip/hip_fp16.h>

#define BB 8
#define C 256
#define HH 56
#define WW 56
#define NN 3136      // HH*WW
#define RR 16
#define NT (NN/16)   // 196 pixel-tiles per image
#define PW 58        // padded spatial width/height

typedef _Float16 half8 __attribute__((ext_vector_type(8)));
typedef _Float16 half4v __attribute__((ext_vector_type(4)));
typedef float floatx4 __attribute__((ext_vector_type(4)));

// ---------------------------------------------------------------------------
// 1. attr branch fused: a = adj( concat( relu(W2 relu(W1 x)), x ) )
// ---------------------------------------------------------------------------
__global__ __launch_bounds__(256) void attr_kernel(
    const float* __restrict__ x,
    const float* __restrict__ w1, const float* __restrict__ b1,
    const float* __restrict__ w2, const float* __restrict__ b2,
    const float* __restrict__ wadj, const float* __restrict__ badj,
    float* __restrict__ a_out)
{
  __shared__ float xs[C][20];
  __shared__ float a2s[C][20];
  __shared__ float a1s[RR][20];
  const int tile = blockIdx.x;
  const int b = tile / NT;
  const int p0 = (tile % NT) * 16;
  const int t = threadIdx.x;

  {
    const float* xb = x + ((size_t)b * C + t) * NN + p0;
    const float4* xb4 = (const float4*)xb;
    float* row = xs[t];
#pragma unroll
    for (int g = 0; g < 4; ++g) {
      float4 v = xb4[g];
      row[g * 4 + 0] = v.x; row[g * 4 + 1] = v.y;
      row[g * 4 + 2] = v.z; row[g * 4 + 3] = v.w;
    }
  }
  __syncthreads();

  {
    const int r = t & 15, pp = t >> 4;
    float acc = b1[r];
    const float* wr = w1 + r * C;
    for (int c = 0; c < C; ++c) acc += wr[c] * xs[c][pp];
    a1s[r][pp] = fmaxf(acc, 0.f);
  }
  __syncthreads();

  {
    const int o = t;
    float acc[16];
    const float bias = b2[o];
#pragma unroll
    for (int p = 0; p < 16; ++p) acc[p] = bias;
    const float* wr = w2 + o * RR;
    for (int k = 0; k < RR; ++k) {
      const float w = wr[k];
#pragma unroll
      for (int p = 0; p < 16; ++p) acc[p] += w * a1s[k][p];
    }
    float* row = a2s[o];
#pragma unroll
    for (int p = 0; p < 16; ++p) row[p] = fmaxf(acc[p], 0.f);
  }
  __syncthreads();

  {
    const int o = t;
    float acc[16];
    const float bias = badj[o];
#pragma unroll
    for (int p = 0; p < 16; ++p) acc[p] = bias;
    const float* wr = wadj + (size_t)o * (2 * C);
    for (int k = 0; k < C; ++k) {
      const float w = wr[k];
      const float4* ar = (const float4*)a2s[k];
#pragma unroll
      for (int g = 0; g < 4; ++g) {
        float4 v = ar[g];
        acc[g * 4 + 0] += w * v.x; acc[g * 4 + 1] += w * v.y;
        acc[g * 4 + 2] += w * v.z; acc[g * 4 + 3] += w * v.w;
      }
    }
    for (int k = 0; k < C; ++k) {
      const float w = wr[C + k];
      const float4* xr = (const float4*)xs[k];
#pragma unroll
      for (int g = 0; g < 4; ++g) {
        float4 v = xr[g];
        acc[g * 4 + 0] += w * v.x; acc[g * 4 + 1] += w * v.y;
        acc[g * 4 + 2] += w * v.z; acc[g * 4 + 3] += w * v.w;
      }
    }
    float* op = a_out + ((size_t)b * C + o) * NN + p0;
    float4* op4 = (float4*)op;
#pragma unroll
    for (int g = 0; g < 4; ++g)
      op4[g] = make_float4(acc[g * 4 + 0], acc[g * 4 + 1], acc[g * 4 + 2], acc[g * 4 + 3]);
  }
}

// ---------------------------------------------------------------------------
// 2a. conv weight prep: w1h[tap][o][c] = tw1[o][c][tap] (fp16)
//     w2h[tap][o][c] = tw2[o][c][8-tap]  (convT spatial flip folded in)
// ---------------------------------------------------------------------------
__global__ __launch_bounds__(256) void wprep_kernel(
    const float* __restrict__ tw1, const float* __restrict__ tw2,
    _Float16* __restrict__ w1h, _Float16* __restrict__ w2h)
{
  const int i = blockIdx.x * 256 + threadIdx.x;   // over 9*256*256
  const int tap = i >> 16;
  const int rem = i & 65535;
  const int o = rem >> 8;
  const int c = rem & 255;
  w1h[i] = (_Float16)tw1[((size_t)o * C + c) * 9 + tap];
  w2h[i] = (_Float16)tw2[((size_t)o * C + c) * 9 + (8 - tap)];
}

// ---------------------------------------------------------------------------
// 2a'. 1x1 weight prep: 7 C*C fp32 matrices -> fp16, same [o][c] layout.
//      Order: qa,ka,va, qt,kt,vt, ow
// ---------------------------------------------------------------------------
__global__ __launch_bounds__(256) void wprep_qkv_kernel(
    const float* __restrict__ m0, const float* __restrict__ m1,
    const float* __restrict__ m2, const float* __restrict__ m3,
    const float* __restrict__ m4, const float* __restrict__ m5,
    const float* __restrict__ m6, _Float16* __restrict__ Whall)
{
  const int i = blockIdx.x * 256 + threadIdx.x;   // over 7*65536
  const int mat = i >> 16, rem = i & 65535;
  const float* s;
  switch (mat) {
    case 0: s = m0; break; case 1: s = m1; break; case 2: s = m2; break;
    case 3: s = m3; break; case 4: s = m4; break; case 5: s = m5; break;
    default: s = m6; break;
  }
  Whall[i] = (_Float16)s[rem];
}

// ---------------------------------------------------------------------------
// 2b. zero the pad border of both padded-NHWC fp16 buffers
// ---------------------------------------------------------------------------
__global__ __launch_bounds__(256) void padzero_kernel(
    _Float16* __restrict__ buf1, _Float16* __restrict__ buf2)
{
  const int bid = blockIdx.x;                 // 2 * BB * PW
  _Float16* buf = (bid < BB * PW) ? buf1 : buf2;
  const int rb = bid % (BB * PW);
  const int b = rb / PW, r = rb % PW;
  _Float16* row = buf + ((size_t)b * PW + r) * PW * C;
  const float4 z = make_float4(0.f, 0.f, 0.f, 0.f);
  if (r == 0 || r == PW - 1) {
    for (int i = threadIdx.x; i < PW * C / 8; i += 256) ((float4*)row)[i] = z;
  } else {
    const int i = threadIdx.x;
    if (i < 32) ((float4*)row)[i] = z;                       // col 0
    else if (i < 64) ((float4*)(row + (PW - 1) * C))[i - 32] = z;  // col 57
  }
}

// ---------------------------------------------------------------------------
// 2c. hn (fp32 NCHW) -> hnpad (fp16 padded NHWC) interior, via LDS transpose
// ---------------------------------------------------------------------------
__global__ __launch_bounds__(256) void hnprep_kernel(
    const float* __restrict__ hn, _Float16* __restrict__ hnpad)
{
  __shared__ float xs[C][17];
  const int tile = blockIdx.x;
  const int b = tile / NT;
  const int p0 = (tile % NT) * 16;
  const int t = threadIdx.x;
  {
    const float4* sb = (const float4*)(hn + ((size_t)b * C + t) * NN + p0);
    float* row = xs[t];
#pragma unroll
    for (int g = 0; g < 4; ++g) {
      float4 v = sb[g];
      row[g * 4 + 0] = v.x; row[g * 4 + 1] = v.y;
      row[g * 4 + 2] = v.z; row[g * 4 + 3] = v.w;
    }
  }
  __syncthreads();
  const int p = t >> 4, c0 = (t & 15) * 16;
  const int pg = p0 + p;
  const int h = pg / WW, w = pg % WW;
  __align__(16) _Float16 tmp[16];
#pragma unroll
  for (int j = 0; j < 16; ++j) tmp[j] = (_Float16)xs[c0 + j][p];
  _Float16* dst = hnpad + (((size_t)b * PW + h + 1) * PW + w + 1) * C + c0;
  ((uint4*)dst)[0] = ((uint4*)tmp)[0];
  ((uint4*)dst)[1] = ((uint4*)tmp)[1];
}

// ---------------------------------------------------------------------------
// 2d. conv3x3 as 9-tap MFMA GEMM.  XCD-swizzled (b = bid & 7).
// ---------------------------------------------------------------------------
__global__ __launch_bounds__(256) void conv_mfma_kernel(
    const _Float16* __restrict__ inpad, const _Float16* __restrict__ wh,
    const float* __restrict__ bias, const float* __restrict__ amul,
    _Float16* __restrict__ out_h, float* __restrict__ out_f, int mode)
{
  const int bid = blockIdx.x;          // BB*56*2
  const int b = bid & 7;               // XCD-aligned batch
  const int rest = bid >> 3;           // 0..111
  const int ohalf = rest & 1;
  const int h = rest >> 1;
  const int t = threadIdx.x;
  const int wave = t >> 6, lane = t & 63;
  const int col = lane & 15, quad = lane >> 4;
  const int o_base = ohalf * 128 + wave * 32;

  floatx4 acc[2][4];
#pragma unroll
  for (int mt = 0; mt < 2; ++mt)
#pragma unroll
    for (int nt = 0; nt < 4; ++nt) acc[mt][nt] = (floatx4){0.f, 0.f, 0.f, 0.f};

  const _Float16* inb = inpad + (size_t)b * PW * PW * C;

  for (int tap = 0; tap < 9; ++tap) {
    const int dy = tap / 3;
    const int dx = tap - dy * 3;
    const _Float16* wtap = wh + (size_t)tap * C * C + quad * 8;
    const _Float16* inrow = inb + ((size_t)(h + dy) * PW + dx + col) * C + quad * 8;
    for (int kc = 0; kc < 8; ++kc) {
      const int c0 = kc * 32;
      const half8 A0 = *(const half8*)(wtap + (size_t)(o_base + col) * C + c0);
      const half8 A1 = *(const half8*)(wtap + (size_t)(o_base + 16 + col) * C + c0);
#pragma unroll
      for (int nt = 0; nt < 4; ++nt) {
        const half8 Bv = *(const half8*)(inrow + (size_t)(nt * 16) * C + c0);
        acc[0][nt] = __builtin_amdgcn_mfma_f32_16x16x32_f16(A0, Bv, acc[0][nt], 0, 0, 0);
        acc[1][nt] = __builtin_amdgcn_mfma_f32_16x16x32_f16(A1, Bv, acc[1][nt], 0, 0, 0);
      }
    }
  }

#pragma unroll
  for (int mt = 0; mt < 2; ++mt) {
    const int o = o_base + mt * 16 + quad * 4;
    const float* bp = bias + o;
    const float b0 = bp[0], b1_ = bp[1], b2_ = bp[2], b3 = bp[3];
    if (mode == 0) {
#pragma unroll
      for (int nt = 0; nt < 4; ++nt) {
        const int wpx = nt * 16 + col;
        if (wpx < WW) {
          __align__(8) _Float16 hv[4];
          hv[0] = (_Float16)fmaxf(acc[mt][nt][0] + b0, 0.f);
          hv[1] = (_Float16)fmaxf(acc[mt][nt][1] + b1_, 0.f);
          hv[2] = (_Float16)fmaxf(acc[mt][nt][2] + b2_, 0.f);
          hv[3] = (_Float16)fmaxf(acc[mt][nt][3] + b3, 0.f);
          _Float16* dst = out_h + (((size_t)b * PW + h + 1) * PW + wpx + 1) * C + o;
          *(uint2*)dst = *(uint2*)hv;
        }
      }
    } else {
#pragma unroll
      for (int nt = 0; nt < 4; ++nt) {
        const int wpx = nt * 16 + col;
        if (wpx < WW) {
          const int p = h * WW + wpx;
          const float bb[4] = {b0, b1_, b2_, b3};
#pragma unroll
          for (int r = 0; r < 4; ++r) {
            const size_t idx = ((size_t)(b * C + o + r)) * NN + p;
            out_f[idx] = (acc[mt][nt][r] + bb[r]) * amul[idx];
          }
        }
      }
    }
  }
}

// ---------------------------------------------------------------------------
// helper: 16B MFMA fragment from LDS as two ds_read_b64 (8B-aligned layouts)
// ---------------------------------------------------------------------------
__device__ inline half8 ld_frag(const _Float16* p) {
  union { half8 h8; half4v h4[2]; } u;
  u.h4[0] = *(const half4v*)p;
  u.h4[1] = *(const half4v*)(p + 4);
  return u.h8;
}

// ---------------------------------------------------------------------------
// 3. qkv as MFMA GEMM. r6 qkv was TA-bound (per-thread weight rows, 64-line
//    gathers). Here: A = fp16 weights [s][o][c] (contiguous rows, L2-hot),
//    B = src tile staged in LDS as fp16 [px][ch], one pass for Q,K,V.
//    Block = 4 waves x (12 m-tiles x 2 n-tiles), 32-px tile, XCD-swizzled.
//    Epilogue: Q,K -> [B][N][C] (8B packed stores), V*0.5 -> Vt [B][C][N].
// ---------------------------------------------------------------------------
__global__ __launch_bounds__(256) void qkv_mfma_kernel(
    const float* __restrict__ src, const _Float16* __restrict__ Wh,
    const float* __restrict__ bq, const float* __restrict__ bk,
    const float* __restrict__ bv,
    __half* __restrict__ Q, __half* __restrict__ K, __half* __restrict__ Vt)
{
  __shared__ _Float16 Ss[32][264];     // [px][ch]  16,896 B
  const int bid = blockIdx.x;          // 784
  const int b = bid & 7;
  const int p0 = (bid >> 3) * 32;
  const int t = threadIdx.x;
  const int w = t >> 6, lane = t & 63;
  const int col = lane & 15, quad = lane >> 4;

  // stage src tile: fp32 [C][N] -> fp16 LDS [px][ch] (thread t = channel t)
  {
    const float4* sp = (const float4*)(src + ((size_t)b * C + t) * NN + p0);
    float v[32];
#pragma unroll
    for (int g = 0; g < 8; ++g) {
      const float4 f = sp[g];
      v[g * 4 + 0] = f.x; v[g * 4 + 1] = f.y;
      v[g * 4 + 2] = f.z; v[g * 4 + 3] = f.w;
    }
#pragma unroll
    for (int px = 0; px < 32; ++px) Ss[px][t] = (_Float16)v[px];
  }
  __syncthreads();

  floatx4 acc[12][2];
#pragma unroll
  for (int i = 0; i < 12; ++i)
#pragma unroll
    for (int nt = 0; nt < 2; ++nt) acc[i][nt] = (floatx4){0.f, 0.f, 0.f, 0.f};

  for (int k0 = 0; k0 < 256; k0 += 32) {
    half8 bf[2];
    bf[0] = ld_frag(&Ss[col][k0 + quad * 8]);
    bf[1] = ld_frag(&Ss[16 + col][k0 + quad * 8]);
#pragma unroll
    for (int i = 0; i < 12; ++i) {
      const int mtg = w * 12 + i;      // 0..47: [0,16)=Q, [16,32)=K, [32,48)=V
      // Wh flat: s*65536 + (mt*16+col)*256 + k  ==  mtg*4096 + col*256 + k
      const half8 af = *(const half8*)(Wh + (size_t)mtg * 4096 + col * 256 + k0 + quad * 8);
      acc[i][0] = __builtin_amdgcn_mfma_f32_16x16x32_f16(af, bf[0], acc[i][0], 0, 0, 0);
      acc[i][1] = __builtin_amdgcn_mfma_f32_16x16x32_f16(af, bf[1], acc[i][1], 0, 0, 0);
    }
  }

#pragma unroll
  for (int i = 0; i < 12; ++i) {
    const int mtg = w * 12 + i;
    const int s = mtg >> 4;
    const int crow = (mtg & 15) * 16 + quad * 4;    // c_out base of this lane
    const float* bp = (s == 0 ? bq : (s == 1 ? bk : bv)) + crow;
    const float4 b4 = *(const float4*)bp;
    const float bb[4] = {b4.x, b4.y, b4.z, b4.w};
#pragma unroll
    for (int nt = 0; nt < 2; ++nt) {
      const int px = p0 + nt * 16 + col;
      if (s == 2) {
#pragma unroll
        for (int r = 0; r < 4; ++r)
          Vt[((size_t)(b * C) + crow + r) * NN + px] =
              __float2half((acc[i][nt][r] + bb[r]) * 0.5f);
      } else {
        __half* dst = (s == 0 ? Q : K) + ((size_t)(b * NN) + px) * C + crow;
        __align__(8) __half hv[4];
#pragma unroll
        for (int r = 0; r < 4; ++r) hv[r] = __float2half(acc[i][nt][r] + bb[r]);
        *(uint2*)dst = *(uint2*)hv;
      }
    }
  }
}

// ---------------------------------------------------------------------------
// 4. Split-K barrier-light flash attention.  2 waves / block: wave 0 owns
//    KV blocks [0,25), wave 1 owns [25,49), each with private (m,l,O).
//    One LDS merge at the end (16 KB buffer):
//       O = (e0*O0 + e1*O1) / (e0*l0 + e1*l1),  e_w = exp(m_w - max(m0,m1)).
//    Rationale (R1 post-mortem): flash was latency-bound at 6.1 waves/CU
//    (grid-limited); K-split doubles resident waves to ~12.25/CU while
//    keeping each XCD's K/V working set at 3.2 MB (L2-resident).
// ---------------------------------------------------------------------------
__global__ __launch_bounds__(128) void flash5_kernel(
    const __half* __restrict__ Qg, const __half* __restrict__ Kg,
    const __half* __restrict__ Vtg, __half* __restrict__ O16, int accumulate)
{
  __shared__ _Float16 Pb[2][16][68];   // per-wave P scratch (4,352 B)
  __shared__ float Os[16][258];        // merge buffer (16,512 B, +2 pad)
  __shared__ float mls[2][16];         // wave1's m,l per q-row

  const int bid = blockIdx.x;          // 8 * 196 = 1568
  const int b = bid & 7;               // XCD-aligned batch
  const int q0 = (bid >> 3) * 16;      // 196 q-tiles of 16 rows
  const int t = threadIdx.x;           // 0..127
  const int w = t >> 6;
  const int lane = t & 63;
  const int col = lane & 15;
  const int quad = lane >> 4;

  const _Float16* Qp = (const _Float16*)Qg + ((size_t)(b * NN) + q0 + col) * C + quad * 8;
  half8 Qf[8];
#pragma unroll
  for (int s = 0; s < 8; ++s) Qf[s] = *(const half8*)(Qp + s * 32);

  floatx4 Ov[16];
#pragma unroll
  for (int n = 0; n < 16; ++n) Ov[n] = (floatx4){0.f, 0.f, 0.f, 0.f};
  float m[4] = {-1e30f, -1e30f, -1e30f, -1e30f};
  float l[4] = {0.f, 0.f, 0.f, 0.f};

  const _Float16* Kb = (const _Float16*)Kg + (size_t)(b * NN) * C;
  const _Float16* Vb = (const _Float16*)Vtg + (size_t)(b * C) * NN;

  const int kbeg = w ? 25 : 0;
  const int kend = w ? 49 : 25;
  for (int kb = kbeg; kb < kend; ++kb) {
    const int key0 = kb * 64;

    // ---- S = Q K^T * scale, 16q x 64k ------------------------------------
    floatx4 Sv[4];
#pragma unroll
    for (int nt = 0; nt < 4; ++nt) {
      floatx4 acc = (floatx4){0.f, 0.f, 0.f, 0.f};
      const _Float16* kp = Kb + (size_t)(key0 + nt * 16 + col) * C + quad * 8;
#pragma unroll
      for (int s = 0; s < 8; ++s) {
        const half8 bf = *(const half8*)(kp + s * 32);
        acc = __builtin_amdgcn_mfma_f32_16x16x32_f16(Qf[s], bf, acc, 0, 0, 0);
      }
      Sv[nt] = acc * 0.0625f;   // 1/sqrt(256)
    }

    // ---- online softmax ---------------------------------------------------
    float f[4];
    bool grow = false;
#pragma unroll
    for (int r = 0; r < 4; ++r) {
      float v = fmaxf(fmaxf(Sv[0][r], Sv[1][r]), fmaxf(Sv[2][r], Sv[3][r]));
      v = fmaxf(v, __shfl_xor(v, 1));
      v = fmaxf(v, __shfl_xor(v, 2));
      v = fmaxf(v, __shfl_xor(v, 4));
      v = fmaxf(v, __shfl_xor(v, 8));
      const float mn = fmaxf(m[r], v);
      f[r] = __expf(m[r] - mn);
      grow = grow || (v > m[r]);
      m[r] = mn;
    }
    float rowsum[4] = {0.f, 0.f, 0.f, 0.f};
#pragma unroll
    for (int nt = 0; nt < 4; ++nt) {
#pragma unroll
      for (int r = 0; r < 4; ++r) {
        const float p = __expf(Sv[nt][r] - m[r]);
        Sv[nt][r] = p;
        rowsum[r] += p;
      }
    }
#pragma unroll
    for (int r = 0; r < 4; ++r) {
      float s = rowsum[r];
      s += __shfl_xor(s, 1);
      s += __shfl_xor(s, 2);
      s += __shfl_xor(s, 4);
      s += __shfl_xor(s, 8);
      l[r] = l[r] * f[r] + s;
    }

    // ---- P -> LDS (acc layout) -> A-fragment layout ------------------------
#pragma unroll
    for (int nt = 0; nt < 4; ++nt)
#pragma unroll
      for (int r = 0; r < 4; ++r)
        Pb[w][quad * 4 + r][nt * 16 + col] = (_Float16)Sv[nt][r];

    if (__any(grow)) {          // T13: skip rescale when max did not grow
      const floatx4 fv = {f[0], f[1], f[2], f[3]};
#pragma unroll
      for (int n = 0; n < 16; ++n) Ov[n] *= fv;
    }

    const half8 pa0 = ld_frag(&Pb[w][col][quad * 8]);
    const half8 pa1 = ld_frag(&Pb[w][col][32 + quad * 8]);

    // ---- O += P V  (V^T fragments straight from L2) -----------------------
#pragma unroll
    for (int nt2 = 0; nt2 < 16; ++nt2) {
      const _Float16* vp = Vb + (size_t)(nt2 * 16 + col) * NN + key0 + quad * 8;
      const half8 bv0 = *(const half8*)(vp);
      const half8 bv1 = *(const half8*)(vp + 32);
      Ov[nt2] = __builtin_amdgcn_mfma_f32_16x16x32_f16(pa0, bv0, Ov[nt2], 0, 0, 0);
      Ov[nt2] = __builtin_amdgcn_mfma_f32_16x16x32_f16(pa1, bv1, Ov[nt2], 0, 0, 0);
    }
  }

  // ---- split-K merge: wave1 publishes, wave0 combines + writes ------------
  if (w == 1) {
    if (col == 0) {
#pragma unroll
      for (int r = 0; r < 4; ++r) {
        mls[0][quad * 4 + r] = m[r];
        mls[1][quad * 4 + r] = l[r];
      }
    }
#pragma unroll
    for (int nt2 = 0; nt2 < 16; ++nt2)
#pragma unroll
      for (int r = 0; r < 4; ++r)
        Os[quad * 4 + r][nt2 * 16 + col] = Ov[nt2][r];
  }
  __syncthreads();
  if (w == 0) {
    float s0[4], s1[4];
#pragma unroll
    for (int r = 0; r < 4; ++r) {
      const int row = quad * 4 + r;
      const float m1 = mls[0][row], l1 = mls[1][row];
      const float M = fmaxf(m[r], m1);
      const float e0 = __expf(m[r] - M), e1 = __expf(m1 - M);
      const float inv = 1.f / (l[r] * e0 + l1 * e1);
      s0[r] = e0 * inv;
      s1[r] = e1 * inv;
    }
#pragma unroll
    for (int nt2 = 0; nt2 < 16; ++nt2) {
#pragma unroll
      for (int r = 0; r < 4; ++r) {
        const int row = quad * 4 + r;
        const float val = Ov[nt2][r] * s0[r] + Os[row][nt2 * 16 + col] * s1[r];
        __half* dst = O16 + ((size_t)(b * NN) + q0 + row) * C + nt2 * 16 + col;
        if (accumulate) *dst = __float2half(val + __half2float(*dst));
        else *dst = __float2half(val);
      }
    }
  }
}

// ---------------------------------------------------------------------------
// 5. out 1x1 conv + residual as MFMA GEMM.
//    A = fp16 ow rows (global), B = O16 [N][C] direct contiguous fragments.
//    Epilogue: + bias + x, write fp32 NCHW o (pre-BN).
// ---------------------------------------------------------------------------
__global__ __launch_bounds__(256) void outconv_mfma_kernel(
    const __half* __restrict__ O16, const _Float16* __restrict__ owh,
    const float* __restrict__ ob, const float* __restrict__ x,
    float* __restrict__ o)
{
  const int bid = blockIdx.x;          // 392
  const int b = bid & 7;
  const int p0 = (bid >> 3) * 64;
  const int t = threadIdx.x;
  const int w = t >> 6, lane = t & 63;
  const int col = lane & 15, quad = lane >> 4;

  floatx4 acc[4][4];
#pragma unroll
  for (int mt = 0; mt < 4; ++mt)
#pragma unroll
    for (int nt = 0; nt < 4; ++nt) acc[mt][nt] = (floatx4){0.f, 0.f, 0.f, 0.f};

  const _Float16* Ob = (const _Float16*)O16 + (size_t)(b * NN) * C;

  for (int k0 = 0; k0 < 256; k0 += 32) {
    half8 bf[4];
#pragma unroll
    for (int nt = 0; nt < 4; ++nt)
      bf[nt] = *(const half8*)(Ob + (size_t)(p0 + nt * 16 + col) * C + k0 + quad * 8);
#pragma unroll
    for (int mt = 0; mt < 4; ++mt) {
      const int crow = w * 64 + mt * 16 + col;
      const half8 af = *(const half8*)(owh + (size_t)crow * 256 + k0 + quad * 8);
#pragma unroll
      for (int nt = 0; nt < 4; ++nt)
        acc[mt][nt] = __builtin_amdgcn_mfma_f32_16x16x32_f16(af, bf[nt], acc[mt][nt], 0, 0, 0);
    }
  }

#pragma unroll
  for (int mt = 0; mt < 4; ++mt) {
    const int c0 = w * 64 + mt * 16 + quad * 4;
    const float4 b4 = *(const float4*)(ob + c0);
    const float bb[4] = {b4.x, b4.y, b4.z, b4.w};
#pragma unroll
    for (int nt = 0; nt < 4; ++nt) {
      const int px = p0 + nt * 16 + col;
#pragma unroll
      for (int r = 0; r < 4; ++r) {
        const size_t idx = ((size_t)(b * C) + c0 + r) * NN + px;
        o[idx] = acc[mt][nt][r] + bb[r] + x[idx];
      }
    }
  }
}

// ---------------------------------------------------------------------------
// 6. BN stats
// ---------------------------------------------------------------------------
__global__ __launch_bounds__(256) void stats_kernel(
    const float* __restrict__ o, float* __restrict__ stats)
{
  const int c = blockIdx.x, t = threadIdx.x;
  float s = 0.f, sq = 0.f;
  for (int b = 0; b < BB; ++b) {
    const float* p = o + ((size_t)b * C + c) * NN;
    for (int idx = t; idx < NN; idx += 256) {
      const float v = p[idx];
      s += v; sq += v * v;
    }
  }
#pragma unroll
  for (int off = 32; off >= 1; off >>= 1) {
    s += __shfl_xor(s, off);
    sq += __shfl_xor(sq, off);
  }
  __shared__ float red[8];
  const int wv = t >> 6;
  if ((t & 63) == 0) { red[wv] = s; red[4 + wv] = sq; }
  __syncthreads();
  if (t == 0) {
    s = red[0] + red[1] + red[2] + red[3];
    sq = red[4] + red[5] + red[6] + red[7];
    stats[c] = s;
    stats[C + c] = sq;
  }
}

// ---------------------------------------------------------------------------
// 7. BN normalize -> d_out
// ---------------------------------------------------------------------------
__global__ __launch_bounds__(256) void bn_kernel(
    const float* __restrict__ o, const float* __restrict__ stats,
    const float* __restrict__ g, const float* __restrict__ bta,
    float* __restrict__ out)
{
  const size_t idx = (size_t)blockIdx.x * 256 + threadIdx.x;
  const float inv_n = 1.f / (float)(BB * NN);
  float4 v = ((const float4*)o)[idx];
  const int c = (int)((idx * 4 / NN) % C);
  const float mean = stats[c] * inv_n;
  const float var = stats[C + c] * inv_n - mean * mean;
  const float sc = rsqrtf(var + 1e-5f) * g[c];
  const float sh = bta[c] - mean * sc;
  v.x = v.x * sc + sh; v.y = v.y * sc + sh;
  v.z = v.z * sc + sh; v.w = v.w * sc + sh;
  ((float4*)out)[idx] = v;
}

// ---------------------------------------------------------------------------
extern "C" void kernel_launch(void* const* d_in, const int* in_sizes, int n_in,
                              void* d_out, int out_size, void* d_ws, size_t ws_size,
                              hipStream_t stream)
{
  const float* x    = (const float*)d_in[0];
  const float* hn   = (const float*)d_in[1];
  const float* w1   = (const float*)d_in[2];  const float* b1   = (const float*)d_in[3];
  const float* w2   = (const float*)d_in[4];  const float* b2   = (const float*)d_in[5];
  const float* wadj = (const float*)d_in[6];  const float* badj = (const float*)d_in[7];
  const float* tw1  = (const float*)d_in[8];  const float* tb1  = (const float*)d_in[9];
  const float* tw2  = (const float*)d_in[10]; const float* tb2  = (const float*)d_in[11];
  const float* qaw  = (const float*)d_in[12]; const float* qab  = (const float*)d_in[13];
  const float* kaw  = (const float*)d_in[14]; const float* kab  = (const float*)d_in[15];
  const float* vaw  = (const float*)d_in[16]; const float* vab  = (const float*)d_in[17];
  const float* qtw  = (const float*)d_in[18]; const float* qtb  = (const float*)d_in[19];
  const float* ktw  = (const float*)d_in[20]; const float* ktb  = (const float*)d_in[21];
  const float* vtw  = (const float*)d_in[22]; const float* vtb  = (const float*)d_in[23];
  const float* ow   = (const float*)d_in[24]; const float* obias= (const float*)d_in[25];
  const float* bng  = (const float*)d_in[26]; const float* bnb  = (const float*)d_in[27];

  // workspace plan (peak ~90.8 MB; 115.6 MB proven in r2/r3):
  //   [a 25.69][tt 25.69][hnpad 13.79+slk][t1pad 13.79+slk][w1h 1.18][w2h 1.18]
  //   Q/K/Vt (38.5) alias hnpad.. after convs; O16 (12.85) aliases a after qkv#1.
  //   [stats 4KB][Whall 0.92MB] appended at the end.
  char* ws = (char*)d_ws;
  const size_t TENS  = (size_t)BB * C * NN * sizeof(float);        // 25,690,112
  const size_t HTENS = (size_t)BB * NN * C * sizeof(__half);       // 12,845,056
  const size_t PADT  = (size_t)BB * PW * PW * C * sizeof(_Float16) // 13,778,944
                       + 16384;                                    // OOB-read slack
  const size_t WT    = (size_t)9 * C * C * sizeof(_Float16);       // 1,179,648
  float*    a     = (float*)(ws);
  float*    tt    = (float*)(ws + TENS);
  _Float16* hnpad = (_Float16*)(ws + 2 * TENS);
  _Float16* t1pad = (_Float16*)(ws + 2 * TENS + PADT);
  _Float16* w1h   = (_Float16*)(ws + 2 * TENS + 2 * PADT);
  _Float16* w2h   = (_Float16*)(ws + 2 * TENS + 2 * PADT + WT);
  __half*   Q     = (__half*)(ws + 2 * TENS);            // aliases hnpad (dead)
  __half*   K     = (__half*)(ws + 2 * TENS + HTENS);
  __half*   Vt    = (__half*)(ws + 2 * TENS + 2 * HTENS);
  float*    stats = (float*)(ws + 2 * TENS + 3 * HTENS);
  _Float16* Whall = (_Float16*)(ws + 2 * TENS + 3 * HTENS + 4096); // 7*65536 fp16
  __half*   O16   = (__half*)a;    // a dead after qkv#1 reads it

  const int PIX_TILES = BB * NT;           // 1568
  const int CONV_BLKS = BB * HH * 2;       // 896
  const int FLASH_BLKS = BB * (NN / 16);   // 1568 (2 waves: split-K halves)
  const int QKV_BLKS = BB * (NN / 32);     // 784
  const int OUT_BLKS = BB * (NN / 64);     // 392

  wprep_kernel<<<9 * C * C / 256, 256, 0, stream>>>(tw1, tw2, w1h, w2h);
  wprep_qkv_kernel<<<7 * C * C / 256, 256, 0, stream>>>(
      qaw, kaw, vaw, qtw, ktw, vtw, ow, Whall);
  padzero_kernel<<<2 * BB * PW, 256, 0, stream>>>(hnpad, t1pad);
  hnprep_kernel<<<PIX_TILES, 256, 0, stream>>>(hn, hnpad);
  attr_kernel<<<PIX_TILES, 256, 0, stream>>>(x, w1, b1, w2, b2, wadj, badj, a);
  conv_mfma_kernel<<<CONV_BLKS, 256, 0, stream>>>(hnpad, w1h, tb1, nullptr, t1pad, nullptr, 0);
  conv_mfma_kernel<<<CONV_BLKS, 256, 0, stream>>>(t1pad, w2h, tb2, a, nullptr, tt, 1);

  qkv_mfma_kernel<<<QKV_BLKS, 256, 0, stream>>>(a, Whall, qab, kab, vab, Q, K, Vt);
  flash5_kernel<<<FLASH_BLKS, 128, 0, stream>>>(Q, K, Vt, O16, 0);
  qkv_mfma_kernel<<<QKV_BLKS, 256, 0, stream>>>(tt, Whall + 3 * 65536, qtb, ktb, vtb, Q, K, Vt);
  flash5_kernel<<<FLASH_BLKS, 128, 0, stream>>>(Q, K, Vt, O16, 1);

  float* o = tt;      // tt dead after qkv#2
  outconv_mfma_kernel<<<OUT_BLKS, 256, 0, stream>>>(O16, Whall + 6 * 65536, obias, x, o);
  stats_kernel<<<C, 256, 0, stream>>>(o, stats);
  bn_kernel<<<(BB * C * NN / 4) / 256, 256, 0, stream>>>(o, stats, bng, bnb, (float*)d_out);
}

// Round 3
// 1524.087 us; speedup vs baseline: 1.5050x; 1.5050x over previous
//
#include <hip/hip_runtime.h>
#include <hip/hip_fp16.h>

#define BB 8
#define C 256
#define HH 56
#define WW 56
#define NN 3136      // HH*WW
#define RR 16
#define NT (NN/16)   // 196 pixel-tiles per image
#define PW 58        // padded spatial width/height

typedef _Float16 half8 __attribute__((ext_vector_type(8)));
typedef _Float16 half4v __attribute__((ext_vector_type(4)));
typedef float floatx4 __attribute__((ext_vector_type(4)));

// ---------------------------------------------------------------------------
// 1. attr branch fused: a = adj( concat( relu(W2 relu(W1 x)), x ) )
// ---------------------------------------------------------------------------
__global__ __launch_bounds__(256) void attr_kernel(
    const float* __restrict__ x,
    const float* __restrict__ w1, const float* __restrict__ b1,
    const float* __restrict__ w2, const float* __restrict__ b2,
    const float* __restrict__ wadj, const float* __restrict__ badj,
    float* __restrict__ a_out)
{
  __shared__ float xs[C][20];
  __shared__ float a2s[C][20];
  __shared__ float a1s[RR][20];
  const int tile = blockIdx.x;
  const int b = tile / NT;
  const int p0 = (tile % NT) * 16;
  const int t = threadIdx.x;

  {
    const float* xb = x + ((size_t)b * C + t) * NN + p0;
    const float4* xb4 = (const float4*)xb;
    float* row = xs[t];
#pragma unroll
    for (int g = 0; g < 4; ++g) {
      float4 v = xb4[g];
      row[g * 4 + 0] = v.x; row[g * 4 + 1] = v.y;
      row[g * 4 + 2] = v.z; row[g * 4 + 3] = v.w;
    }
  }
  __syncthreads();

  {
    const int r = t & 15, pp = t >> 4;
    float acc = b1[r];
    const float* wr = w1 + r * C;
    for (int c = 0; c < C; ++c) acc += wr[c] * xs[c][pp];
    a1s[r][pp] = fmaxf(acc, 0.f);
  }
  __syncthreads();

  {
    const int o = t;
    float acc[16];
    const float bias = b2[o];
#pragma unroll
    for (int p = 0; p < 16; ++p) acc[p] = bias;
    const float* wr = w2 + o * RR;
    for (int k = 0; k < RR; ++k) {
      const float w = wr[k];
#pragma unroll
      for (int p = 0; p < 16; ++p) acc[p] += w * a1s[k][p];
    }
    float* row = a2s[o];
#pragma unroll
    for (int p = 0; p < 16; ++p) row[p] = fmaxf(acc[p], 0.f);
  }
  __syncthreads();

  {
    const int o = t;
    float acc[16];
    const float bias = badj[o];
#pragma unroll
    for (int p = 0; p < 16; ++p) acc[p] = bias;
    const float* wr = wadj + (size_t)o * (2 * C);
    for (int k = 0; k < C; ++k) {
      const float w = wr[k];
      const float4* ar = (const float4*)a2s[k];
#pragma unroll
      for (int g = 0; g < 4; ++g) {
        float4 v = ar[g];
        acc[g * 4 + 0] += w * v.x; acc[g * 4 + 1] += w * v.y;
        acc[g * 4 + 2] += w * v.z; acc[g * 4 + 3] += w * v.w;
      }
    }
    for (int k = 0; k < C; ++k) {
      const float w = wr[C + k];
      const float4* xr = (const float4*)xs[k];
#pragma unroll
      for (int g = 0; g < 4; ++g) {
        float4 v = xr[g];
        acc[g * 4 + 0] += w * v.x; acc[g * 4 + 1] += w * v.y;
        acc[g * 4 + 2] += w * v.z; acc[g * 4 + 3] += w * v.w;
      }
    }
    float* op = a_out + ((size_t)b * C + o) * NN + p0;
    float4* op4 = (float4*)op;
#pragma unroll
    for (int g = 0; g < 4; ++g)
      op4[g] = make_float4(acc[g * 4 + 0], acc[g * 4 + 1], acc[g * 4 + 2], acc[g * 4 + 3]);
  }
}

// ---------------------------------------------------------------------------
// 2a. conv weight prep: w1h[tap][o][c] = tw1[o][c][tap] (fp16)
//     w2h[tap][o][c] = tw2[o][c][8-tap]  (convT spatial flip folded in)
// ---------------------------------------------------------------------------
__global__ __launch_bounds__(256) void wprep_kernel(
    const float* __restrict__ tw1, const float* __restrict__ tw2,
    _Float16* __restrict__ w1h, _Float16* __restrict__ w2h)
{
  const int i = blockIdx.x * 256 + threadIdx.x;   // over 9*256*256
  const int tap = i >> 16;
  const int rem = i & 65535;
  const int o = rem >> 8;
  const int c = rem & 255;
  w1h[i] = (_Float16)tw1[((size_t)o * C + c) * 9 + tap];
  w2h[i] = (_Float16)tw2[((size_t)o * C + c) * 9 + (8 - tap)];
}

// ---------------------------------------------------------------------------
// 2a'. 1x1 weight prep: 7 C*C fp32 matrices -> fp16, same [o][c] layout.
//      Order: qa,ka,va, qt,kt,vt, ow
// ---------------------------------------------------------------------------
__global__ __launch_bounds__(256) void wprep_qkv_kernel(
    const float* __restrict__ m0, const float* __restrict__ m1,
    const float* __restrict__ m2, const float* __restrict__ m3,
    const float* __restrict__ m4, const float* __restrict__ m5,
    const float* __restrict__ m6, _Float16* __restrict__ Whall)
{
  const int i = blockIdx.x * 256 + threadIdx.x;   // over 7*65536
  const int mat = i >> 16, rem = i & 65535;
  const float* s;
  switch (mat) {
    case 0: s = m0; break; case 1: s = m1; break; case 2: s = m2; break;
    case 3: s = m3; break; case 4: s = m4; break; case 5: s = m5; break;
    default: s = m6; break;
  }
  Whall[i] = (_Float16)s[rem];
}

// ---------------------------------------------------------------------------
// 2b. zero the pad border of both padded-NHWC fp16 buffers
// ---------------------------------------------------------------------------
__global__ __launch_bounds__(256) void padzero_kernel(
    _Float16* __restrict__ buf1, _Float16* __restrict__ buf2)
{
  const int bid = blockIdx.x;                 // 2 * BB * PW
  _Float16* buf = (bid < BB * PW) ? buf1 : buf2;
  const int rb = bid % (BB * PW);
  const int b = rb / PW, r = rb % PW;
  _Float16* row = buf + ((size_t)b * PW + r) * PW * C;
  const float4 z = make_float4(0.f, 0.f, 0.f, 0.f);
  if (r == 0 || r == PW - 1) {
    for (int i = threadIdx.x; i < PW * C / 8; i += 256) ((float4*)row)[i] = z;
  } else {
    const int i = threadIdx.x;
    if (i < 32) ((float4*)row)[i] = z;                       // col 0
    else if (i < 64) ((float4*)(row + (PW - 1) * C))[i - 32] = z;  // col 57
  }
}

// ---------------------------------------------------------------------------
// 2c. hn (fp32 NCHW) -> hnpad (fp16 padded NHWC) interior, via LDS transpose
// ---------------------------------------------------------------------------
__global__ __launch_bounds__(256) void hnprep_kernel(
    const float* __restrict__ hn, _Float16* __restrict__ hnpad)
{
  __shared__ float xs[C][17];
  const int tile = blockIdx.x;
  const int b = tile / NT;
  const int p0 = (tile % NT) * 16;
  const int t = threadIdx.x;
  {
    const float4* sb = (const float4*)(hn + ((size_t)b * C + t) * NN + p0);
    float* row = xs[t];
#pragma unroll
    for (int g = 0; g < 4; ++g) {
      float4 v = sb[g];
      row[g * 4 + 0] = v.x; row[g * 4 + 1] = v.y;
      row[g * 4 + 2] = v.z; row[g * 4 + 3] = v.w;
    }
  }
  __syncthreads();
  const int p = t >> 4, c0 = (t & 15) * 16;
  const int pg = p0 + p;
  const int h = pg / WW, w = pg % WW;
  __align__(16) _Float16 tmp[16];
#pragma unroll
  for (int j = 0; j < 16; ++j) tmp[j] = (_Float16)xs[c0 + j][p];
  _Float16* dst = hnpad + (((size_t)b * PW + h + 1) * PW + w + 1) * C + c0;
  ((uint4*)dst)[0] = ((uint4*)tmp)[0];
  ((uint4*)dst)[1] = ((uint4*)tmp)[1];
}

// ---------------------------------------------------------------------------
// 2d. conv3x3 as 9-tap MFMA GEMM.  XCD-swizzled (b = bid & 7).
// ---------------------------------------------------------------------------
__global__ __launch_bounds__(256) void conv_mfma_kernel(
    const _Float16* __restrict__ inpad, const _Float16* __restrict__ wh,
    const float* __restrict__ bias, const float* __restrict__ amul,
    _Float16* __restrict__ out_h, float* __restrict__ out_f, int mode)
{
  const int bid = blockIdx.x;          // BB*56*2
  const int b = bid & 7;               // XCD-aligned batch
  const int rest = bid >> 3;           // 0..111
  const int ohalf = rest & 1;
  const int h = rest >> 1;
  const int t = threadIdx.x;
  const int wave = t >> 6, lane = t & 63;
  const int col = lane & 15, quad = lane >> 4;
  const int o_base = ohalf * 128 + wave * 32;

  floatx4 acc[2][4];
#pragma unroll
  for (int mt = 0; mt < 2; ++mt)
#pragma unroll
    for (int nt = 0; nt < 4; ++nt) acc[mt][nt] = (floatx4){0.f, 0.f, 0.f, 0.f};

  const _Float16* inb = inpad + (size_t)b * PW * PW * C;

  for (int tap = 0; tap < 9; ++tap) {
    const int dy = tap / 3;
    const int dx = tap - dy * 3;
    const _Float16* wtap = wh + (size_t)tap * C * C + quad * 8;
    const _Float16* inrow = inb + ((size_t)(h + dy) * PW + dx + col) * C + quad * 8;
    for (int kc = 0; kc < 8; ++kc) {
      const int c0 = kc * 32;
      const half8 A0 = *(const half8*)(wtap + (size_t)(o_base + col) * C + c0);
      const half8 A1 = *(const half8*)(wtap + (size_t)(o_base + 16 + col) * C + c0);
#pragma unroll
      for (int nt = 0; nt < 4; ++nt) {
        const half8 Bv = *(const half8*)(inrow + (size_t)(nt * 16) * C + c0);
        acc[0][nt] = __builtin_amdgcn_mfma_f32_16x16x32_f16(A0, Bv, acc[0][nt], 0, 0, 0);
        acc[1][nt] = __builtin_amdgcn_mfma_f32_16x16x32_f16(A1, Bv, acc[1][nt], 0, 0, 0);
      }
    }
  }

#pragma unroll
  for (int mt = 0; mt < 2; ++mt) {
    const int o = o_base + mt * 16 + quad * 4;
    const float* bp = bias + o;
    const float b0 = bp[0], b1_ = bp[1], b2_ = bp[2], b3 = bp[3];
    if (mode == 0) {
#pragma unroll
      for (int nt = 0; nt < 4; ++nt) {
        const int wpx = nt * 16 + col;
        if (wpx < WW) {
          __align__(8) _Float16 hv[4];
          hv[0] = (_Float16)fmaxf(acc[mt][nt][0] + b0, 0.f);
          hv[1] = (_Float16)fmaxf(acc[mt][nt][1] + b1_, 0.f);
          hv[2] = (_Float16)fmaxf(acc[mt][nt][2] + b2_, 0.f);
          hv[3] = (_Float16)fmaxf(acc[mt][nt][3] + b3, 0.f);
          _Float16* dst = out_h + (((size_t)b * PW + h + 1) * PW + wpx + 1) * C + o;
          *(uint2*)dst = *(uint2*)hv;
        }
      }
    } else {
#pragma unroll
      for (int nt = 0; nt < 4; ++nt) {
        const int wpx = nt * 16 + col;
        if (wpx < WW) {
          const int p = h * WW + wpx;
          const float bb[4] = {b0, b1_, b2_, b3};
#pragma unroll
          for (int r = 0; r < 4; ++r) {
            const size_t idx = ((size_t)(b * C + o + r)) * NN + p;
            out_f[idx] = (acc[mt][nt][r] + bb[r]) * amul[idx];
          }
        }
      }
    }
  }
}

// ---------------------------------------------------------------------------
// helper: 16B MFMA fragment from LDS as two ds_read_b64 (8B-aligned layouts)
// ---------------------------------------------------------------------------
__device__ inline half8 ld_frag(const _Float16* p) {
  union { half8 h8; half4v h4[2]; } u;
  u.h4[0] = *(const half4v*)p;
  u.h4[1] = *(const half4v*)(p + 4);
  return u.h8;
}

// ---------------------------------------------------------------------------
// 3. qkv as MFMA GEMM. r6 qkv was TA-bound (per-thread weight rows, 64-line
//    gathers). Here: A = fp16 weights [s][o][c] (contiguous rows, L2-hot),
//    B = src tile staged in LDS as fp16 [px][ch], one pass for Q,K,V.
//    Block = 4 waves x (12 m-tiles x 2 n-tiles), 32-px tile, XCD-swizzled.
//    Epilogue: Q,K -> [B][N][C] (8B packed stores), V*0.5 -> Vt [B][C][N].
// ---------------------------------------------------------------------------
__global__ __launch_bounds__(256) void qkv_mfma_kernel(
    const float* __restrict__ src, const _Float16* __restrict__ Wh,
    const float* __restrict__ bq, const float* __restrict__ bk,
    const float* __restrict__ bv,
    __half* __restrict__ Q, __half* __restrict__ K, __half* __restrict__ Vt)
{
  __shared__ _Float16 Ss[32][264];     // [px][ch]  16,896 B
  const int bid = blockIdx.x;          // 784
  const int b = bid & 7;
  const int p0 = (bid >> 3) * 32;
  const int t = threadIdx.x;
  const int w = t >> 6, lane = t & 63;
  const int col = lane & 15, quad = lane >> 4;

  // stage src tile: fp32 [C][N] -> fp16 LDS [px][ch] (thread t = channel t)
  {
    const float4* sp = (const float4*)(src + ((size_t)b * C + t) * NN + p0);
    float v[32];
#pragma unroll
    for (int g = 0; g < 8; ++g) {
      const float4 f = sp[g];
      v[g * 4 + 0] = f.x; v[g * 4 + 1] = f.y;
      v[g * 4 + 2] = f.z; v[g * 4 + 3] = f.w;
    }
#pragma unroll
    for (int px = 0; px < 32; ++px) Ss[px][t] = (_Float16)v[px];
  }
  __syncthreads();

  floatx4 acc[12][2];
#pragma unroll
  for (int i = 0; i < 12; ++i)
#pragma unroll
    for (int nt = 0; nt < 2; ++nt) acc[i][nt] = (floatx4){0.f, 0.f, 0.f, 0.f};

  for (int k0 = 0; k0 < 256; k0 += 32) {
    half8 bf[2];
    bf[0] = ld_frag(&Ss[col][k0 + quad * 8]);
    bf[1] = ld_frag(&Ss[16 + col][k0 + quad * 8]);
#pragma unroll
    for (int i = 0; i < 12; ++i) {
      const int mtg = w * 12 + i;      // 0..47: [0,16)=Q, [16,32)=K, [32,48)=V
      // Wh flat: s*65536 + (mt*16+col)*256 + k  ==  mtg*4096 + col*256 + k
      const half8 af = *(const half8*)(Wh + (size_t)mtg * 4096 + col * 256 + k0 + quad * 8);
      acc[i][0] = __builtin_amdgcn_mfma_f32_16x16x32_f16(af, bf[0], acc[i][0], 0, 0, 0);
      acc[i][1] = __builtin_amdgcn_mfma_f32_16x16x32_f16(af, bf[1], acc[i][1], 0, 0, 0);
    }
  }

#pragma unroll
  for (int i = 0; i < 12; ++i) {
    const int mtg = w * 12 + i;
    const int s = mtg >> 4;
    const int crow = (mtg & 15) * 16 + quad * 4;    // c_out base of this lane
    const float* bp = (s == 0 ? bq : (s == 1 ? bk : bv)) + crow;
    const float4 b4 = *(const float4*)bp;
    const float bb[4] = {b4.x, b4.y, b4.z, b4.w};
#pragma unroll
    for (int nt = 0; nt < 2; ++nt) {
      const int px = p0 + nt * 16 + col;
      if (s == 2) {
#pragma unroll
        for (int r = 0; r < 4; ++r)
          Vt[((size_t)(b * C) + crow + r) * NN + px] =
              __float2half((acc[i][nt][r] + bb[r]) * 0.5f);
      } else {
        __half* dst = (s == 0 ? Q : K) + ((size_t)(b * NN) + px) * C + crow;
        __align__(8) __half hv[4];
#pragma unroll
        for (int r = 0; r < 4; ++r) hv[r] = __float2half(acc[i][nt][r] + bb[r]);
        *(uint2*)dst = *(uint2*)hv;
      }
    }
  }
}

// ---------------------------------------------------------------------------
// 4. Shared-LDS flash attention.  R2 post-mortem: flash4/5 were bound by
//    per-CU L1-miss handling (~30 GB/s/CU of L2-hit traffic) because every
//    wave privately streamed K+V (19 MB/CU).  Fix = reuse: 7 waves share one
//    staged K/V tile.  QBLK=112 (7 waves x 16 q-rows, 448 thr), KVBLK=64.
//    224 blocks -> 1 block/CU, single round; per-CU L2 fetch 3.2 MB (6x cut).
//    Staging is reg-prefetched under compute (T14).  Bank-balanced pads:
//    Ks stride 528B, Vs 144B, Pb 136B (all hit the b128 structural floor).
// ---------------------------------------------------------------------------
__global__ __launch_bounds__(448) void flash6_kernel(
    const __half* __restrict__ Qg, const __half* __restrict__ Kg,
    const __half* __restrict__ Vtg, __half* __restrict__ O16, int accumulate)
{
  __shared__ _Float16 Ks[64][264];     // [key][ch]   33,792 B
  __shared__ _Float16 Vs[256][72];     // [ch][key]   36,864 B
  __shared__ _Float16 Pb[7][16][68];   // per-wave P  15,232 B

  const int bid = blockIdx.x;          // 8 * 28 = 224
  const int b = bid & 7;               // XCD-aligned batch
  const int q0 = (bid >> 3) * 112;     // 28 q-tiles of 112 rows
  const int t = threadIdx.x;           // 0..447
  const int w = t >> 6;                // wave 0..6
  const int lane = t & 63;
  const int col = lane & 15;
  const int quad = lane >> 4;

  const _Float16* Kb = (const _Float16*)Kg + (size_t)(b * NN) * C;
  const _Float16* Vb = (const _Float16*)Vtg + (size_t)(b * C) * NN;

  // Q fragments for this wave's 16 rows (held in regs for all 49 iters)
  const _Float16* Qp = (const _Float16*)Qg +
      ((size_t)(b * NN) + q0 + w * 16 + col) * C + quad * 8;
  half8 Qf[8];
#pragma unroll
  for (int s = 0; s < 8; ++s) Qf[s] = *(const half8*)(Qp + s * 32);

  floatx4 Ov[16];
#pragma unroll
  for (int n = 0; n < 16; ++n) Ov[n] = (floatx4){0.f, 0.f, 0.f, 0.f};
  float m[4] = {-1e30f, -1e30f, -1e30f, -1e30f};
  float l[4] = {0.f, 0.f, 0.f, 0.f};

  // staging registers: K tile = 64x256 fp16 = 2048 x 16B chunks, V same.
  uint4 kr[5], vr[5];

  auto loadK = [&](int key0) {
#pragma unroll
    for (int j = 0; j < 5; ++j) {
      const int i = j * 448 + t;
      if (i < 2048) {
        const int key = i >> 5, off = i & 31;
        kr[j] = *(const uint4*)(Kb + (size_t)(key0 + key) * C + off * 8);
      }
    }
  };
  auto loadV = [&](int key0) {
#pragma unroll
    for (int j = 0; j < 5; ++j) {
      const int i = j * 448 + t;
      if (i < 2048) {
        const int ch = i >> 3, off = i & 7;
        vr[j] = *(const uint4*)(Vb + (size_t)ch * NN + key0 + off * 8);
      }
    }
  };
  auto storeKV = [&]() {
#pragma unroll
    for (int j = 0; j < 5; ++j) {
      const int i = j * 448 + t;
      if (i < 2048) {
        const int key = i >> 5, koff = i & 31;
        *(uint4*)&Ks[key][koff * 8] = kr[j];
        const int ch = i >> 3, voff = i & 7;
        *(uint4*)&Vs[ch][voff * 8] = vr[j];
      }
    }
  };

  loadK(0);
  loadV(0);

  for (int kb = 0; kb < 49; ++kb) {
    __syncthreads();                   // prev iter's LDS reads complete
    storeKV();
    __syncthreads();                   // tile visible to all waves
    if (kb + 1 < 49) {                 // prefetch next tile under compute
      loadK((kb + 1) * 64);
      loadV((kb + 1) * 64);
    }

    // ---- S = Q K^T * scale, 16q x 64k (K from LDS) ------------------------
    floatx4 Sv[4];
#pragma unroll
    for (int nt = 0; nt < 4; ++nt) {
      floatx4 acc = (floatx4){0.f, 0.f, 0.f, 0.f};
#pragma unroll
      for (int s = 0; s < 8; ++s) {
        const half8 bf = *(const half8*)&Ks[nt * 16 + col][s * 32 + quad * 8];
        acc = __builtin_amdgcn_mfma_f32_16x16x32_f16(Qf[s], bf, acc, 0, 0, 0);
      }
      Sv[nt] = acc * 0.0625f;   // 1/sqrt(256)
    }

    // ---- online softmax ---------------------------------------------------
    float f[4];
    bool grow = false;
#pragma unroll
    for (int r = 0; r < 4; ++r) {
      float v = fmaxf(fmaxf(Sv[0][r], Sv[1][r]), fmaxf(Sv[2][r], Sv[3][r]));
      v = fmaxf(v, __shfl_xor(v, 1));
      v = fmaxf(v, __shfl_xor(v, 2));
      v = fmaxf(v, __shfl_xor(v, 4));
      v = fmaxf(v, __shfl_xor(v, 8));
      const float mn = fmaxf(m[r], v);
      f[r] = __expf(m[r] - mn);
      grow = grow || (v > m[r]);
      m[r] = mn;
    }
    float rowsum[4] = {0.f, 0.f, 0.f, 0.f};
#pragma unroll
    for (int nt = 0; nt < 4; ++nt) {
#pragma unroll
      for (int r = 0; r < 4; ++r) {
        const float p = __expf(Sv[nt][r] - m[r]);
        Sv[nt][r] = p;
        rowsum[r] += p;
      }
    }
#pragma unroll
    for (int r = 0; r < 4; ++r) {
      float s = rowsum[r];
      s += __shfl_xor(s, 1);
      s += __shfl_xor(s, 2);
      s += __shfl_xor(s, 4);
      s += __shfl_xor(s, 8);
      l[r] = l[r] * f[r] + s;
    }

    // ---- P -> per-wave LDS scratch -> A-fragment layout --------------------
#pragma unroll
    for (int nt = 0; nt < 4; ++nt)
#pragma unroll
      for (int r = 0; r < 4; ++r)
        Pb[w][quad * 4 + r][nt * 16 + col] = (_Float16)Sv[nt][r];

    if (__any(grow)) {          // T13: skip rescale when max did not grow
      const floatx4 fv = {f[0], f[1], f[2], f[3]};
#pragma unroll
      for (int n = 0; n < 16; ++n) Ov[n] *= fv;
    }

    const half8 pa0 = ld_frag(&Pb[w][col][quad * 8]);
    const half8 pa1 = ld_frag(&Pb[w][col][32 + quad * 8]);

    // ---- O += P V  (V^T fragments from LDS) -------------------------------
#pragma unroll
    for (int nt2 = 0; nt2 < 16; ++nt2) {
      const half8 bv0 = *(const half8*)&Vs[nt2 * 16 + col][quad * 8];
      const half8 bv1 = *(const half8*)&Vs[nt2 * 16 + col][32 + quad * 8];
      Ov[nt2] = __builtin_amdgcn_mfma_f32_16x16x32_f16(pa0, bv0, Ov[nt2], 0, 0, 0);
      Ov[nt2] = __builtin_amdgcn_mfma_f32_16x16x32_f16(pa1, bv1, Ov[nt2], 0, 0, 0);
    }
  }

  float inv[4];
#pragma unroll
  for (int r = 0; r < 4; ++r) inv[r] = 1.f / l[r];
#pragma unroll
  for (int nt2 = 0; nt2 < 16; ++nt2) {
#pragma unroll
    for (int r = 0; r < 4; ++r) {
      const float val = Ov[nt2][r] * inv[r];
      __half* dst = O16 + ((size_t)(b * NN) + q0 + w * 16 + quad * 4 + r) * C +
                    nt2 * 16 + col;
      if (accumulate) *dst = __float2half(val + __half2float(*dst));
      else *dst = __float2half(val);
    }
  }
}

// ---------------------------------------------------------------------------
// 5. out 1x1 conv + residual as MFMA GEMM.
//    A = fp16 ow rows (global), B = O16 [N][C] direct contiguous fragments.
//    Epilogue: + bias + x, write fp32 NCHW o (pre-BN).
// ---------------------------------------------------------------------------
__global__ __launch_bounds__(256) void outconv_mfma_kernel(
    const __half* __restrict__ O16, const _Float16* __restrict__ owh,
    const float* __restrict__ ob, const float* __restrict__ x,
    float* __restrict__ o)
{
  const int bid = blockIdx.x;          // 392
  const int b = bid & 7;
  const int p0 = (bid >> 3) * 64;
  const int t = threadIdx.x;
  const int w = t >> 6, lane = t & 63;
  const int col = lane & 15, quad = lane >> 4;

  floatx4 acc[4][4];
#pragma unroll
  for (int mt = 0; mt < 4; ++mt)
#pragma unroll
    for (int nt = 0; nt < 4; ++nt) acc[mt][nt] = (floatx4){0.f, 0.f, 0.f, 0.f};

  const _Float16* Ob = (const _Float16*)O16 + (size_t)(b * NN) * C;

  for (int k0 = 0; k0 < 256; k0 += 32) {
    half8 bf[4];
#pragma unroll
    for (int nt = 0; nt < 4; ++nt)
      bf[nt] = *(const half8*)(Ob + (size_t)(p0 + nt * 16 + col) * C + k0 + quad * 8);
#pragma unroll
    for (int mt = 0; mt < 4; ++mt) {
      const int crow = w * 64 + mt * 16 + col;
      const half8 af = *(const half8*)(owh + (size_t)crow * 256 + k0 + quad * 8);
#pragma unroll
      for (int nt = 0; nt < 4; ++nt)
        acc[mt][nt] = __builtin_amdgcn_mfma_f32_16x16x32_f16(af, bf[nt], acc[mt][nt], 0, 0, 0);
    }
  }

#pragma unroll
  for (int mt = 0; mt < 4; ++mt) {
    const int c0 = w * 64 + mt * 16 + quad * 4;
    const float4 b4 = *(const float4*)(ob + c0);
    const float bb[4] = {b4.x, b4.y, b4.z, b4.w};
#pragma unroll
    for (int nt = 0; nt < 4; ++nt) {
      const int px = p0 + nt * 16 + col;
#pragma unroll
      for (int r = 0; r < 4; ++r) {
        const size_t idx = ((size_t)(b * C) + c0 + r) * NN + px;
        o[idx] = acc[mt][nt][r] + bb[r] + x[idx];
      }
    }
  }
}

// ---------------------------------------------------------------------------
// 6. BN stats
// ---------------------------------------------------------------------------
__global__ __launch_bounds__(256) void stats_kernel(
    const float* __restrict__ o, float* __restrict__ stats)
{
  const int c = blockIdx.x, t = threadIdx.x;
  float s = 0.f, sq = 0.f;
  for (int b = 0; b < BB; ++b) {
    const float* p = o + ((size_t)b * C + c) * NN;
    for (int idx = t; idx < NN; idx += 256) {
      const float v = p[idx];
      s += v; sq += v * v;
    }
  }
#pragma unroll
  for (int off = 32; off >= 1; off >>= 1) {
    s += __shfl_xor(s, off);
    sq += __shfl_xor(sq, off);
  }
  __shared__ float red[8];
  const int wv = t >> 6;
  if ((t & 63) == 0) { red[wv] = s; red[4 + wv] = sq; }
  __syncthreads();
  if (t == 0) {
    s = red[0] + red[1] + red[2] + red[3];
    sq = red[4] + red[5] + red[6] + red[7];
    stats[c] = s;
    stats[C + c] = sq;
  }
}

// ---------------------------------------------------------------------------
// 7. BN normalize -> d_out
// ---------------------------------------------------------------------------
__global__ __launch_bounds__(256) void bn_kernel(
    const float* __restrict__ o, const float* __restrict__ stats,
    const float* __restrict__ g, const float* __restrict__ bta,
    float* __restrict__ out)
{
  const size_t idx = (size_t)blockIdx.x * 256 + threadIdx.x;
  const float inv_n = 1.f / (float)(BB * NN);
  float4 v = ((const float4*)o)[idx];
  const int c = (int)((idx * 4 / NN) % C);
  const float mean = stats[c] * inv_n;
  const float var = stats[C + c] * inv_n - mean * mean;
  const float sc = rsqrtf(var + 1e-5f) * g[c];
  const float sh = bta[c] - mean * sc;
  v.x = v.x * sc + sh; v.y = v.y * sc + sh;
  v.z = v.z * sc + sh; v.w = v.w * sc + sh;
  ((float4*)out)[idx] = v;
}

// ---------------------------------------------------------------------------
extern "C" void kernel_launch(void* const* d_in, const int* in_sizes, int n_in,
                              void* d_out, int out_size, void* d_ws, size_t ws_size,
                              hipStream_t stream)
{
  const float* x    = (const float*)d_in[0];
  const float* hn   = (const float*)d_in[1];
  const float* w1   = (const float*)d_in[2];  const float* b1   = (const float*)d_in[3];
  const float* w2   = (const float*)d_in[4];  const float* b2   = (const float*)d_in[5];
  const float* wadj = (const float*)d_in[6];  const float* badj = (const float*)d_in[7];
  const float* tw1  = (const float*)d_in[8];  const float* tb1  = (const float*)d_in[9];
  const float* tw2  = (const float*)d_in[10]; const float* tb2  = (const float*)d_in[11];
  const float* qaw  = (const float*)d_in[12]; const float* qab  = (const float*)d_in[13];
  const float* kaw  = (const float*)d_in[14]; const float* kab  = (const float*)d_in[15];
  const float* vaw  = (const float*)d_in[16]; const float* vab  = (const float*)d_in[17];
  const float* qtw  = (const float*)d_in[18]; const float* qtb  = (const float*)d_in[19];
  const float* ktw  = (const float*)d_in[20]; const float* ktb  = (const float*)d_in[21];
  const float* vtw  = (const float*)d_in[22]; const float* vtb  = (const float*)d_in[23];
  const float* ow   = (const float*)d_in[24]; const float* obias= (const float*)d_in[25];
  const float* bng  = (const float*)d_in[26]; const float* bnb  = (const float*)d_in[27];

  // workspace plan (peak ~90.8 MB; 115.6 MB proven in r2/r3):
  //   [a 25.69][tt 25.69][hnpad 13.79+slk][t1pad 13.79+slk][w1h 1.18][w2h 1.18]
  //   Q/K/Vt (38.5) alias hnpad.. after convs; O16 (12.85) aliases a after qkv#1.
  //   [stats 4KB][Whall 0.92MB] appended at the end.
  char* ws = (char*)d_ws;
  const size_t TENS  = (size_t)BB * C * NN * sizeof(float);        // 25,690,112
  const size_t HTENS = (size_t)BB * NN * C * sizeof(__half);       // 12,845,056
  const size_t PADT  = (size_t)BB * PW * PW * C * sizeof(_Float16) // 13,778,944
                       + 16384;                                    // OOB-read slack
  const size_t WT    = (size_t)9 * C * C * sizeof(_Float16);       // 1,179,648
  float*    a     = (float*)(ws);
  float*    tt    = (float*)(ws + TENS);
  _Float16* hnpad = (_Float16*)(ws + 2 * TENS);
  _Float16* t1pad = (_Float16*)(ws + 2 * TENS + PADT);
  _Float16* w1h   = (_Float16*)(ws + 2 * TENS + 2 * PADT);
  _Float16* w2h   = (_Float16*)(ws + 2 * TENS + 2 * PADT + WT);
  __half*   Q     = (__half*)(ws + 2 * TENS);            // aliases hnpad (dead)
  __half*   K     = (__half*)(ws + 2 * TENS + HTENS);
  __half*   Vt    = (__half*)(ws + 2 * TENS + 2 * HTENS);
  float*    stats = (float*)(ws + 2 * TENS + 3 * HTENS);
  _Float16* Whall = (_Float16*)(ws + 2 * TENS + 3 * HTENS + 4096); // 7*65536 fp16
  __half*   O16   = (__half*)a;    // a dead after qkv#1 reads it

  const int PIX_TILES = BB * NT;           // 1568
  const int CONV_BLKS = BB * HH * 2;       // 896
  const int FLASH_BLKS = BB * (NN / 112);  // 224 (7 waves x 16 q-rows each)
  const int QKV_BLKS = BB * (NN / 32);     // 784
  const int OUT_BLKS = BB * (NN / 64);     // 392

  wprep_kernel<<<9 * C * C / 256, 256, 0, stream>>>(tw1, tw2, w1h, w2h);
  wprep_qkv_kernel<<<7 * C * C / 256, 256, 0, stream>>>(
      qaw, kaw, vaw, qtw, ktw, vtw, ow, Whall);
  padzero_kernel<<<2 * BB * PW, 256, 0, stream>>>(hnpad, t1pad);
  hnprep_kernel<<<PIX_TILES, 256, 0, stream>>>(hn, hnpad);
  attr_kernel<<<PIX_TILES, 256, 0, stream>>>(x, w1, b1, w2, b2, wadj, badj, a);
  conv_mfma_kernel<<<CONV_BLKS, 256, 0, stream>>>(hnpad, w1h, tb1, nullptr, t1pad, nullptr, 0);
  conv_mfma_kernel<<<CONV_BLKS, 256, 0, stream>>>(t1pad, w2h, tb2, a, nullptr, tt, 1);

  qkv_mfma_kernel<<<QKV_BLKS, 256, 0, stream>>>(a, Whall, qab, kab, vab, Q, K, Vt);
  flash6_kernel<<<FLASH_BLKS, 448, 0, stream>>>(Q, K, Vt, O16, 0);
  qkv_mfma_kernel<<<QKV_BLKS, 256, 0, stream>>>(tt, Whall + 3 * 65536, qtb, ktb, vtb, Q, K, Vt);
  flash6_kernel<<<FLASH_BLKS, 448, 0, stream>>>(Q, K, Vt, O16, 1);

  float* o = tt;      // tt dead after qkv#2
  outconv_mfma_kernel<<<OUT_BLKS, 256, 0, stream>>>(O16, Whall + 6 * 65536, obias, x, o);
  stats_kernel<<<C, 256, 0, stream>>>(o, stats);
  bn_kernel<<<(BB * C * NN / 4) / 256, 256, 0, stream>>>(o, stats, bng, bnb, (float*)d_out);
}